// Round 6
// baseline (287.936 us; speedup 1.0000x reference)
//
#include <hip/hip_runtime.h>

#define N_NODES 512
#define INNER   256
#define IN_DIM  128
#define EDGE_DIM 64
#define NH 8
#define HD 32
#define SCALE 0.17677669529663687f  // 1/sqrt(32)

// ---------------------------------------------------------------------------
// K0: q/k/v projections. Block (m, i-tile of 8). nodes tile in LDS (broadcast
// reads), W coalesced 1 KB/wave, outputs coalesced. 192 blocks x 256 thr.
// ---------------------------------------------------------------------------
__global__ __launch_bounds__(256) void proj_qkv(
    const float* __restrict__ nodes,
    const float* __restrict__ Wq, const float* __restrict__ bq,
    const float* __restrict__ Wk, const float* __restrict__ bk,
    const float* __restrict__ Wv, const float* __restrict__ bv,
    float* __restrict__ q, float* __restrict__ k, float* __restrict__ v) {
  const int m  = blockIdx.x >> 6;
  const int i0 = (blockIdx.x & 63) * 8;
  const int n  = threadIdx.x;
  const float* __restrict__ W = (m == 0) ? Wq : (m == 1) ? Wk : Wv;
  const float* __restrict__ b = (m == 0) ? bq : (m == 1) ? bk : bv;
  float*       __restrict__ o = (m == 0) ? q  : (m == 1) ? k  : v;

  __shared__ float s_n[8 * IN_DIM];
  *(float4*)&s_n[n * 4] = *(const float4*)&nodes[(size_t)i0 * IN_DIM + n * 4];
  __syncthreads();

  float acc[8] = {0.f, 0.f, 0.f, 0.f, 0.f, 0.f, 0.f, 0.f};
#pragma unroll 4
  for (int c = 0; c < IN_DIM; ++c) {
    const float w = W[(size_t)c * INNER + n];
#pragma unroll
    for (int r = 0; r < 8; ++r) acc[r] = fmaf(s_n[r * IN_DIM + c], w, acc[r]);
  }
  const float bn = b[n];
#pragma unroll
  for (int r = 0; r < 8; ++r) o[(size_t)(i0 + r) * INNER + n] = acc[r] + bn;
}

// ---------------------------------------------------------------------------
// K0b: qe[i,h,c] = sum_d q[i,h*32+d]*We[c,h*32+d]; qb[i,h] = q_ih . be_h.
// 8 i per block; We segment held in registers, reused 8x. 64 blocks x 512 thr.
// ---------------------------------------------------------------------------
__global__ __launch_bounds__(512) void qe_qb(
    const float* __restrict__ q, const float* __restrict__ We,
    const float* __restrict__ be,
    float* __restrict__ qe, float* __restrict__ qb) {
  const int i0  = blockIdx.x * 8;
  const int tid = threadIdx.x;

  __shared__ float s_q[8 * INNER];
  *(float4*)&s_q[tid * 4] = *(const float4*)&q[(size_t)i0 * INNER + tid * 4];
  __syncthreads();

  const int h = tid >> 6, c = tid & 63;
  float4 w[8];
#pragma unroll
  for (int d4 = 0; d4 < 8; ++d4)
    w[d4] = *(const float4*)&We[(size_t)c * INNER + h * HD + d4 * 4];

#pragma unroll
  for (int il = 0; il < 8; ++il) {
    const float* qh = &s_q[il * INNER + h * HD];
    float acc = 0.f;
#pragma unroll
    for (int d4 = 0; d4 < 8; ++d4) {
      const float4 q4 = *(const float4*)&qh[d4 * 4];
      acc += q4.x * w[d4].x + q4.y * w[d4].y + q4.z * w[d4].z + q4.w * w[d4].w;
    }
    qe[(size_t)(i0 + il) * (NH * EDGE_DIM) + h * EDGE_DIM + c] = acc;
  }

  if (tid < 64) {
    const int il = tid >> 3, h2 = tid & 7;
    float acc = 0.f;
    for (int d = 0; d < HD; ++d)
      acc += s_q[il * INNER + h2 * HD + d] * be[h2 * HD + d];
    qb[(size_t)(i0 + il) * NH + h2] = acc;
  }
}

// ---------------------------------------------------------------------------
// K1: qk[i,h,j] = q_ih . k_jh (unscaled). 16x16 (i,j) tile, LDS-staged,
// fully coalesced. 1024 blocks x 256 thr.
// ---------------------------------------------------------------------------
__global__ __launch_bounds__(256) void qk_gemm(
    const float* __restrict__ q, const float* __restrict__ k,
    float* __restrict__ qk) {
  const int it = blockIdx.x >> 5, jt = blockIdx.x & 31;
  const int i0 = it * 16, j0 = jt * 16;
  const int tid = threadIdx.x;

  __shared__ float sq[16 * 260];  // stride 260: b128-aligned, bank-spread
  __shared__ float sk[16 * 260];
#pragma unroll
  for (int p = 0; p < 4; ++p) {
    const int s = tid + p * 256;            // float4 slot 0..1023
    const int row = s >> 6, c4 = s & 63;
    *(float4*)&sq[row * 260 + c4 * 4] =
        *(const float4*)&q[(size_t)(i0 + row) * INNER + c4 * 4];
    *(float4*)&sk[row * 260 + c4 * 4] =
        *(const float4*)&k[(size_t)(j0 + row) * INNER + c4 * 4];
  }
  __syncthreads();

  const int il = tid >> 4, jl = tid & 15;
  float acc[NH];
#pragma unroll
  for (int h = 0; h < NH; ++h) {
    float s = 0.f;
#pragma unroll
    for (int d4 = 0; d4 < 8; ++d4) {
      const float4 q4 = *(const float4*)&sq[il * 260 + h * HD + d4 * 4];
      const float4 k4 = *(const float4*)&sk[jl * 260 + h * HD + d4 * 4];
      s += q4.x * k4.x + q4.y * k4.y + q4.z * k4.z + q4.w * k4.w;
    }
    acc[h] = s;
  }
#pragma unroll
  for (int h = 0; h < NH; ++h)
    qk[(size_t)(i0 + il) * (NH * N_NODES) + h * N_NODES + j0 + jl] = acc[h];
}

// ---------------------------------------------------------------------------
// K2: single-pass fused attention. Block per i, 512 thr, 4 chunks of 128 j.
// Mean quirk cancels algebraically -> no pre-pass; edges read ONCE.
//   p[h,j] = exp((qk + edges.qe + qb)*scale) * adj
//   out[n] = (sum_j p*v[j,n])/hsum + (ae/hsum)@We[:,n] + 1{hsum>0}*be[n]
// ---------------------------------------------------------------------------
__global__ __launch_bounds__(512, 4) void fused_attn(
    const float* __restrict__ edges, const int* __restrict__ adjacency,
    const float* __restrict__ v,
    const float* __restrict__ qe, const float* __restrict__ qb,
    const float* __restrict__ qkbuf,
    const float* __restrict__ We, const float* __restrict__ be,
    float* __restrict__ out) {
  const int i   = blockIdx.x;
  const int tid = threadIdx.x;

  __shared__ float s_qe[NH * EDGE_DIM];
  __shared__ float s_qb[NH];
  __shared__ float s_adj[N_NODES];
  __shared__ float e_tile[128 * 68];     // stride 68: b128-aligned, 2-way max
  __shared__ float p_lds[NH * 128];
  __shared__ float s_hred[8][2];
  __shared__ float s_rd[NH];
  __shared__ float s_as[NH];
  __shared__ float s_aered[8][NH * EDGE_DIM];
  __shared__ float s_avp[2][INNER];
  __shared__ float s_ae[NH * EDGE_DIM];

  s_qe[tid]  = qe[(size_t)i * (NH * EDGE_DIM) + tid];
  s_adj[tid] = (float)adjacency[(size_t)i * N_NODES + tid];
  if (tid < NH) s_qb[tid] = qb[(size_t)i * NH + tid];

  const int hg  = tid >> 7, j_l = tid & 127, h0 = hg * 2;   // phase A role
  const int cA  = tid & 63, part = tid >> 6;                // phase B role
  const int nC  = tid & 255, p2 = tid >> 8, hv = nC >> 5;   // phase C role

  float hs0 = 0.f, hs1 = 0.f, accv = 0.f;
  float accae[NH] = {0.f, 0.f, 0.f, 0.f, 0.f, 0.f, 0.f, 0.f};

  for (int jc = 0; jc < 4; ++jc) {
    __syncthreads();  // protect e_tile/p_lds from prior-chunk readers
    // ---- stage edges chunk: 128 rows x 64 c (contiguous 32 KB) ----
    const float* esrc = edges + (size_t)i * (N_NODES * EDGE_DIM) + jc * (128 * EDGE_DIM);
#pragma unroll
    for (int p = 0; p < 4; ++p) {
      const int s = tid + p * 512;           // float4 slot 0..2047
      const int r = s >> 4, c4 = s & 15;
      *(float4*)&e_tile[r * 68 + c4 * 4] = *(const float4*)&esrc[s * 4];
    }
    __syncthreads();

    // ---- phase A: p for 2 heads at j = jc*128 + j_l ----
    {
      const float* er  = &e_tile[j_l * 68];
      const float* qe0 = &s_qe[h0 * EDGE_DIM];
      const float* qe1 = qe0 + EDGE_DIM;
      float s0 = 0.f, s1 = 0.f;
#pragma unroll
      for (int c4 = 0; c4 < 16; ++c4) {
        const float4 e4 = *(const float4*)&er[c4 * 4];
        const float4 a0 = *(const float4*)&qe0[c4 * 4];
        const float4 a1 = *(const float4*)&qe1[c4 * 4];
        s0 += e4.x * a0.x + e4.y * a0.y + e4.z * a0.z + e4.w * a0.w;
        s1 += e4.x * a1.x + e4.y * a1.y + e4.z * a1.z + e4.w * a1.w;
      }
      const int jg = jc * 128 + j_l;
      const float qk0 = qkbuf[(size_t)i * (NH * N_NODES) + h0 * N_NODES + jg];
      const float qk1 = qkbuf[(size_t)i * (NH * N_NODES) + (h0 + 1) * N_NODES + jg];
      const float aj = s_adj[jg];
      const float p0 = __expf((s0 + qk0 + s_qb[h0]) * SCALE) * aj;
      const float p1 = __expf((s1 + qk1 + s_qb[h0 + 1]) * SCALE) * aj;
      p_lds[h0 * 128 + j_l]       = p0;
      p_lds[(h0 + 1) * 128 + j_l] = p1;
      hs0 += p0; hs1 += p1;
    }
    __syncthreads();

    // ---- phase B: ae[h][cA] partial over 16 j (register-accumulated) ----
    {
      const int jb = part * 16;
#pragma unroll
      for (int jj4 = 0; jj4 < 4; ++jj4) {
        const int jr = jb + jj4 * 4;
        const float e0 = e_tile[(jr + 0) * 68 + cA];
        const float e1 = e_tile[(jr + 1) * 68 + cA];
        const float e2 = e_tile[(jr + 2) * 68 + cA];
        const float e3 = e_tile[(jr + 3) * 68 + cA];
#pragma unroll
        for (int h = 0; h < NH; ++h) {
          const float4 p4 = *(const float4*)&p_lds[h * 128 + jr];
          accae[h] = fmaf(p4.x, e0, accae[h]);
          accae[h] = fmaf(p4.y, e1, accae[h]);
          accae[h] = fmaf(p4.z, e2, accae[h]);
          accae[h] = fmaf(p4.w, e3, accae[h]);
        }
      }
    }
    // ---- phase C: av[nC] partial over 64 j (v coalesced) ----
    {
      const float* vc = v + (size_t)(jc * 128 + p2 * 64) * INNER + nC;
      const float* pr = &p_lds[hv * 128 + p2 * 64];
#pragma unroll 4
      for (int jj4 = 0; jj4 < 16; ++jj4) {
        const float4 p4 = *(const float4*)&pr[jj4 * 4];
        accv = fmaf(p4.x, vc[(size_t)(jj4 * 4 + 0) * INNER], accv);
        accv = fmaf(p4.y, vc[(size_t)(jj4 * 4 + 1) * INNER], accv);
        accv = fmaf(p4.z, vc[(size_t)(jj4 * 4 + 2) * INNER], accv);
        accv = fmaf(p4.w, vc[(size_t)(jj4 * 4 + 3) * INNER], accv);
      }
    }
  }

  // ---- hsum reduction: waves 2g,2g+1 hold heads {2g,2g+1} over 128 j ----
  {
    float a = hs0, b = hs1;
#pragma unroll
    for (int off = 32; off > 0; off >>= 1) {
      a += __shfl_xor(a, off, 64);
      b += __shfl_xor(b, off, 64);
    }
    if ((tid & 63) == 0) { s_hred[tid >> 6][0] = a; s_hred[tid >> 6][1] = b; }
  }
  __syncthreads();
  if (tid < NH) {
    const int g = tid >> 1, r = tid & 1;
    const float t = s_hred[g * 2][r] + s_hred[g * 2 + 1][r];
    s_rd[tid] = (t == 0.f) ? 1.f : (1.f / t);
    s_as[tid] = (t == 0.f) ? 0.f : 1.f;
  }
#pragma unroll
  for (int h = 0; h < NH; ++h) s_aered[part][h * EDGE_DIM + cA] = accae[h];
  s_avp[p2][nC] = accv;
  __syncthreads();

  // ---- combine ae partials, normalize ----
  {
    float t = 0.f;
#pragma unroll
    for (int pt = 0; pt < 8; ++pt) t += s_aered[pt][tid];
    s_ae[tid] = t * s_rd[tid >> 6];
  }
  __syncthreads();

  // ---- epilogue ----
  if (tid < INNER) {
    const int n = tid, h = n >> 5;
    float o = (s_avp[0][n] + s_avp[1][n]) * s_rd[h] + s_as[h] * be[n];
    const float* aeh = &s_ae[h * EDGE_DIM];
#pragma unroll 8
    for (int cc = 0; cc < EDGE_DIM; ++cc)
      o = fmaf(aeh[cc], We[(size_t)cc * INNER + n], o);
    out[(size_t)i * INNER + n] = o;
  }
}

extern "C" void kernel_launch(void* const* d_in, const int* in_sizes, int n_in,
                              void* d_out, int out_size, void* d_ws, size_t ws_size,
                              hipStream_t stream) {
  const float* nodes     = (const float*)d_in[0];
  const float* edges     = (const float*)d_in[1];
  const int*   adjacency = (const int*)d_in[2];
  const float* Wq = (const float*)d_in[3];
  const float* bq = (const float*)d_in[4];
  const float* Wk = (const float*)d_in[5];
  const float* bk = (const float*)d_in[6];
  const float* Wv = (const float*)d_in[7];
  const float* bv = (const float*)d_in[8];
  const float* We = (const float*)d_in[9];
  const float* be = (const float*)d_in[10];

  float* q   = (float*)d_ws;                      // 512*256
  float* k   = q   + (size_t)N_NODES * INNER;     // 512*256
  float* v   = k   + (size_t)N_NODES * INNER;     // 512*256
  float* qe  = v   + (size_t)N_NODES * INNER;     // 512*512
  float* qb  = qe  + (size_t)N_NODES * NH * EDGE_DIM;  // 512*8
  float* qkb = qb  + (size_t)N_NODES * NH;        // 512*8*512

  proj_qkv<<<dim3(3 * 64), dim3(256), 0, stream>>>(
      nodes, Wq, bq, Wk, bk, Wv, bv, q, k, v);
  qe_qb<<<dim3(64), dim3(512), 0, stream>>>(q, We, be, qe, qb);
  qk_gemm<<<dim3(1024), dim3(256), 0, stream>>>(q, k, qkb);
  fused_attn<<<dim3(N_NODES), dim3(512), 0, stream>>>(
      edges, adjacency, v, qe, qb, qkb, We, be, (float*)d_out);
}

// Round 7
// 158.956 us; speedup vs baseline: 1.8114x; 1.8114x over previous
//
#include <hip/hip_runtime.h>

#define N_NODES 512
#define INNER   256
#define IN_DIM  128
#define EDGE_DIM 64
#define NH 8
#define HD 32
#define SCALE 0.17677669529663687f  // 1/sqrt(32)

// ---------------------------------------------------------------------------
// K0: q/k/v projections. Block (m, i-tile of 8). nodes tile in LDS (broadcast
// reads), W coalesced, outputs coalesced. 192 blocks x 256 thr.
// ---------------------------------------------------------------------------
__global__ __launch_bounds__(256) void proj_qkv(
    const float* __restrict__ nodes,
    const float* __restrict__ Wq, const float* __restrict__ bq,
    const float* __restrict__ Wk, const float* __restrict__ bk,
    const float* __restrict__ Wv, const float* __restrict__ bv,
    float* __restrict__ q, float* __restrict__ k, float* __restrict__ v) {
  const int m  = blockIdx.x >> 6;
  const int i0 = (blockIdx.x & 63) * 8;
  const int n  = threadIdx.x;
  const float* __restrict__ W = (m == 0) ? Wq : (m == 1) ? Wk : Wv;
  const float* __restrict__ b = (m == 0) ? bq : (m == 1) ? bk : bv;
  float*       __restrict__ o = (m == 0) ? q  : (m == 1) ? k  : v;

  __shared__ float s_n[8 * IN_DIM];
  *(float4*)&s_n[n * 4] = *(const float4*)&nodes[(size_t)i0 * IN_DIM + n * 4];
  __syncthreads();

  float acc[8] = {0.f, 0.f, 0.f, 0.f, 0.f, 0.f, 0.f, 0.f};
#pragma unroll 4
  for (int c = 0; c < IN_DIM; ++c) {
    const float w = W[(size_t)c * INNER + n];
#pragma unroll
    for (int r = 0; r < 8; ++r) acc[r] = fmaf(s_n[r * IN_DIM + c], w, acc[r]);
  }
  const float bn = b[n];
#pragma unroll
  for (int r = 0; r < 8; ++r) o[(size_t)(i0 + r) * INNER + n] = acc[r] + bn;
}

// ---------------------------------------------------------------------------
// K0b: qe[i,h,c] = q_ih . We[c, h*32..]; qb[i,h] = q_ih . be_h.
// ---------------------------------------------------------------------------
__global__ __launch_bounds__(512) void qe_qb(
    const float* __restrict__ q, const float* __restrict__ We,
    const float* __restrict__ be,
    float* __restrict__ qe, float* __restrict__ qb) {
  const int i0  = blockIdx.x * 8;
  const int tid = threadIdx.x;

  __shared__ float s_q[8 * INNER];
  *(float4*)&s_q[tid * 4] = *(const float4*)&q[(size_t)i0 * INNER + tid * 4];
  __syncthreads();

  const int h = tid >> 6, c = tid & 63;
  float4 w[8];
#pragma unroll
  for (int d4 = 0; d4 < 8; ++d4)
    w[d4] = *(const float4*)&We[(size_t)c * INNER + h * HD + d4 * 4];

#pragma unroll
  for (int il = 0; il < 8; ++il) {
    const float* qh = &s_q[il * INNER + h * HD];
    float acc = 0.f;
#pragma unroll
    for (int d4 = 0; d4 < 8; ++d4) {
      const float4 q4 = *(const float4*)&qh[d4 * 4];
      acc += q4.x * w[d4].x + q4.y * w[d4].y + q4.z * w[d4].z + q4.w * w[d4].w;
    }
    qe[(size_t)(i0 + il) * (NH * EDGE_DIM) + h * EDGE_DIM + c] = acc;
  }

  if (tid < 64) {
    const int il = tid >> 3, h2 = tid & 7;
    float acc = 0.f;
    for (int d = 0; d < HD; ++d)
      acc += s_q[il * INNER + h2 * HD + d] * be[h2 * HD + d];
    qb[(size_t)(i0 + il) * NH + h2] = acc;
  }
}

// ---------------------------------------------------------------------------
// K1: qk[i,h,j] = q_ih . k_jh (unscaled). 16x16 tile, LDS-staged, coalesced.
// ---------------------------------------------------------------------------
__global__ __launch_bounds__(256) void qk_gemm(
    const float* __restrict__ q, const float* __restrict__ k,
    float* __restrict__ qk) {
  const int it = blockIdx.x >> 5, jt = blockIdx.x & 31;
  const int i0 = it * 16, j0 = jt * 16;
  const int tid = threadIdx.x;

  __shared__ float sq[16 * 260];
  __shared__ float sk[16 * 260];
#pragma unroll
  for (int p = 0; p < 4; ++p) {
    const int s = tid + p * 256;
    const int row = s >> 6, c4 = s & 63;
    *(float4*)&sq[row * 260 + c4 * 4] =
        *(const float4*)&q[(size_t)(i0 + row) * INNER + c4 * 4];
    *(float4*)&sk[row * 260 + c4 * 4] =
        *(const float4*)&k[(size_t)(j0 + row) * INNER + c4 * 4];
  }
  __syncthreads();

  const int il = tid >> 4, jl = tid & 15;
  float acc[NH];
#pragma unroll
  for (int h = 0; h < NH; ++h) {
    float s = 0.f;
#pragma unroll
    for (int d4 = 0; d4 < 8; ++d4) {
      const float4 q4 = *(const float4*)&sq[il * 260 + h * HD + d4 * 4];
      const float4 k4 = *(const float4*)&sk[jl * 260 + h * HD + d4 * 4];
      s += q4.x * k4.x + q4.y * k4.y + q4.z * k4.z + q4.w * k4.w;
    }
    acc[h] = s;
  }
#pragma unroll
  for (int h = 0; h < NH; ++h)
    qk[(size_t)(i0 + il) * (NH * N_NODES) + h * N_NODES + j0 + jl] = acc[h];
}

// ---------------------------------------------------------------------------
// K2: single-pass fused attention, SCALAR accumulators only (no spill).
// Block per i, 512 thr, 4 chunks of 128 j; edges read ONCE.
// Roles per chunk:
//   A: thread=(head-pair hg, j_l)  -> p[h,j], running hsums (2 scalars)
//   B: thread=(head hB, col cB)    -> accae scalar over 128 j
//   C: thread=(col nC, half p2)    -> accv scalar over 64 j
// ---------------------------------------------------------------------------
__global__ __launch_bounds__(512, 4) void fused_attn(
    const float* __restrict__ edges, const int* __restrict__ adjacency,
    const float* __restrict__ v,
    const float* __restrict__ qe, const float* __restrict__ qb,
    const float* __restrict__ qkbuf,
    const float* __restrict__ We, const float* __restrict__ be,
    float* __restrict__ out) {
  const int i   = blockIdx.x;
  const int tid = threadIdx.x;

  __shared__ float s_qe[NH * EDGE_DIM];
  __shared__ float s_qb[NH];
  __shared__ float s_adj[N_NODES];
  __shared__ float e_tile[128 * 68];   // stride 68 floats
  __shared__ float p_lds[NH * 128];
  __shared__ float s_hred[8][2];
  __shared__ float s_rd[NH];
  __shared__ float s_as[NH];
  __shared__ float s_avp[2][INNER];
  __shared__ float s_ae[NH * EDGE_DIM];

  s_qe[tid]  = qe[(size_t)i * (NH * EDGE_DIM) + tid];
  s_adj[tid] = (float)adjacency[(size_t)i * N_NODES + tid];
  if (tid < NH) s_qb[tid] = qb[(size_t)i * NH + tid];

  const int j_l = tid & 127, hg = tid >> 7, h0 = hg * 2;  // phase A
  const int cB  = tid & 63,  hB = tid >> 6;               // phase B
  const int nC  = tid & 255, p2 = tid >> 8, hv = nC >> 5; // phase C

  float hs0 = 0.f, hs1 = 0.f, accv = 0.f, accae = 0.f;

  for (int jc = 0; jc < 4; ++jc) {
    __syncthreads();  // prior-chunk readers of e_tile/p_lds done
    // ---- stage edges chunk (contiguous 32 KB) ----
    const float* esrc = edges + (size_t)i * (N_NODES * EDGE_DIM) + jc * (128 * EDGE_DIM);
#pragma unroll
    for (int p = 0; p < 4; ++p) {
      const int s = tid + p * 512;
      const int r = s >> 4, c4 = s & 15;
      *(float4*)&e_tile[r * 68 + c4 * 4] = *(const float4*)&esrc[s * 4];
    }
    __syncthreads();

    // ---- phase A: p for 2 heads at j = jc*128 + j_l ----
    {
      const float* er  = &e_tile[j_l * 68];
      const float* qe0 = &s_qe[h0 * EDGE_DIM];
      const float* qe1 = qe0 + EDGE_DIM;
      float s0 = 0.f, s1 = 0.f;
#pragma unroll 4
      for (int c4 = 0; c4 < 16; ++c4) {
        const float4 e4 = *(const float4*)&er[c4 * 4];
        const float4 a0 = *(const float4*)&qe0[c4 * 4];
        const float4 a1 = *(const float4*)&qe1[c4 * 4];
        s0 += e4.x * a0.x + e4.y * a0.y + e4.z * a0.z + e4.w * a0.w;
        s1 += e4.x * a1.x + e4.y * a1.y + e4.z * a1.z + e4.w * a1.w;
      }
      const int jg = jc * 128 + j_l;
      const float qk0 = qkbuf[(size_t)i * (NH * N_NODES) + h0 * N_NODES + jg];
      const float qk1 = qkbuf[(size_t)i * (NH * N_NODES) + (h0 + 1) * N_NODES + jg];
      const float aj = s_adj[jg];
      const float p0 = __expf((s0 + qk0 + s_qb[h0]) * SCALE) * aj;
      const float p1 = __expf((s1 + qk1 + s_qb[h0 + 1]) * SCALE) * aj;
      p_lds[h0 * 128 + j_l]       = p0;
      p_lds[(h0 + 1) * 128 + j_l] = p1;
      hs0 += p0; hs1 += p1;
    }
    __syncthreads();

    // ---- phase B: accae (scalar) over 128 j for (hB, cB) ----
    {
      const float* pb = &p_lds[hB * 128];
      const float* eb = &e_tile[cB];
#pragma unroll 8
      for (int j4 = 0; j4 < 32; ++j4) {
        const float4 p4 = *(const float4*)&pb[j4 * 4];
        accae = fmaf(p4.x, eb[(j4 * 4 + 0) * 68], accae);
        accae = fmaf(p4.y, eb[(j4 * 4 + 1) * 68], accae);
        accae = fmaf(p4.z, eb[(j4 * 4 + 2) * 68], accae);
        accae = fmaf(p4.w, eb[(j4 * 4 + 3) * 68], accae);
      }
    }
    // ---- phase C: accv (scalar) over 64 j for column nC ----
    {
      const float* vc = v + (size_t)(jc * 128 + p2 * 64) * INNER + nC;
      const float* pr = &p_lds[hv * 128 + p2 * 64];
#pragma unroll 4
      for (int jj4 = 0; jj4 < 16; ++jj4) {
        const float4 p4 = *(const float4*)&pr[jj4 * 4];
        accv = fmaf(p4.x, vc[(size_t)(jj4 * 4 + 0) * INNER], accv);
        accv = fmaf(p4.y, vc[(size_t)(jj4 * 4 + 1) * INNER], accv);
        accv = fmaf(p4.z, vc[(size_t)(jj4 * 4 + 2) * INNER], accv);
        accv = fmaf(p4.w, vc[(size_t)(jj4 * 4 + 3) * INNER], accv);
      }
    }
  }

  // ---- hsum reduction (phase-A roles: waves 2g,2g+1 hold heads 2g,2g+1) ----
  {
    float a = hs0, b = hs1;
#pragma unroll
    for (int off = 32; off > 0; off >>= 1) {
      a += __shfl_xor(a, off, 64);
      b += __shfl_xor(b, off, 64);
    }
    if ((tid & 63) == 0) { s_hred[tid >> 6][0] = a; s_hred[tid >> 6][1] = b; }
  }
  s_avp[p2][nC] = accv;
  __syncthreads();
  if (tid < NH) {
    const int g = tid >> 1, r = tid & 1;
    const float t = s_hred[g * 2][r] + s_hred[g * 2 + 1][r];
    s_rd[tid] = (t == 0.f) ? 1.f : (1.f / t);
    s_as[tid] = (t == 0.f) ? 0.f : 1.f;
  }
  __syncthreads();

  // ---- normalized ae (index h*64+c == tid) ----
  s_ae[tid] = accae * s_rd[hB];
  __syncthreads();

  // ---- epilogue ----
  if (tid < INNER) {
    const int n = tid, h = n >> 5;
    float o = (s_avp[0][n] + s_avp[1][n]) * s_rd[h] + s_as[h] * be[n];
    const float* aeh = &s_ae[h * EDGE_DIM];
#pragma unroll 8
    for (int cc = 0; cc < EDGE_DIM; ++cc)
      o = fmaf(aeh[cc], We[(size_t)cc * INNER + n], o);
    out[(size_t)i * INNER + n] = o;
  }
}

extern "C" void kernel_launch(void* const* d_in, const int* in_sizes, int n_in,
                              void* d_out, int out_size, void* d_ws, size_t ws_size,
                              hipStream_t stream) {
  const float* nodes     = (const float*)d_in[0];
  const float* edges     = (const float*)d_in[1];
  const int*   adjacency = (const int*)d_in[2];
  const float* Wq = (const float*)d_in[3];
  const float* bq = (const float*)d_in[4];
  const float* Wk = (const float*)d_in[5];
  const float* bk = (const float*)d_in[6];
  const float* Wv = (const float*)d_in[7];
  const float* bv = (const float*)d_in[8];
  const float* We = (const float*)d_in[9];
  const float* be = (const float*)d_in[10];

  float* q   = (float*)d_ws;                           // 512*256
  float* k   = q   + (size_t)N_NODES * INNER;          // 512*256
  float* v   = k   + (size_t)N_NODES * INNER;          // 512*256
  float* qe  = v   + (size_t)N_NODES * INNER;          // 512*512
  float* qb  = qe  + (size_t)N_NODES * NH * EDGE_DIM;  // 512*8
  float* qkb = qb  + (size_t)N_NODES * NH;             // 512*8*512

  proj_qkv<<<dim3(3 * 64), dim3(256), 0, stream>>>(
      nodes, Wq, bq, Wk, bk, Wv, bv, q, k, v);
  qe_qb<<<dim3(64), dim3(512), 0, stream>>>(q, We, be, qe, qb);
  qk_gemm<<<dim3(1024), dim3(256), 0, stream>>>(q, k, qkb);
  fused_attn<<<dim3(N_NODES), dim3(512), 0, stream>>>(
      edges, adjacency, v, qe, qb, qkb, We, be, (float*)d_out);
}

// Round 8
// 158.246 us; speedup vs baseline: 1.8196x; 1.0045x over previous
//
#include <hip/hip_runtime.h>

#define N_NODES 512
#define INNER   256
#define IN_DIM  128
#define EDGE_DIM 64
#define NH 8
#define HD 32
#define SCALE 0.17677669529663687f  // 1/sqrt(32)

// ---------------------------------------------------------------------------
// K0: q/k/v projections. Block (m, i-tile of 8). nodes tile in LDS (broadcast
// reads), W coalesced, outputs coalesced. 192 blocks x 256 thr.
// ---------------------------------------------------------------------------
__global__ __launch_bounds__(256) void proj_qkv(
    const float* __restrict__ nodes,
    const float* __restrict__ Wq, const float* __restrict__ bq,
    const float* __restrict__ Wk, const float* __restrict__ bk,
    const float* __restrict__ Wv, const float* __restrict__ bv,
    float* __restrict__ q, float* __restrict__ k, float* __restrict__ v) {
  const int m  = blockIdx.x >> 6;
  const int i0 = (blockIdx.x & 63) * 8;
  const int n  = threadIdx.x;
  const float* __restrict__ W = (m == 0) ? Wq : (m == 1) ? Wk : Wv;
  const float* __restrict__ b = (m == 0) ? bq : (m == 1) ? bk : bv;
  float*       __restrict__ o = (m == 0) ? q  : (m == 1) ? k  : v;

  __shared__ float s_n[8 * IN_DIM];
  *(float4*)&s_n[n * 4] = *(const float4*)&nodes[(size_t)i0 * IN_DIM + n * 4];
  __syncthreads();

  float acc[8] = {0.f, 0.f, 0.f, 0.f, 0.f, 0.f, 0.f, 0.f};
#pragma unroll 4
  for (int c = 0; c < IN_DIM; ++c) {
    const float w = W[(size_t)c * INNER + n];
#pragma unroll
    for (int r = 0; r < 8; ++r) acc[r] = fmaf(s_n[r * IN_DIM + c], w, acc[r]);
  }
  const float bn = b[n];
#pragma unroll
  for (int r = 0; r < 8; ++r) o[(size_t)(i0 + r) * INNER + n] = acc[r] + bn;
}

// ---------------------------------------------------------------------------
// K0b: qe[i,h,c] = q_ih . We[c, h*32..]; qb[i,h] = q_ih . be_h.
// ---------------------------------------------------------------------------
__global__ __launch_bounds__(512) void qe_qb(
    const float* __restrict__ q, const float* __restrict__ We,
    const float* __restrict__ be,
    float* __restrict__ qe, float* __restrict__ qb) {
  const int i0  = blockIdx.x * 8;
  const int tid = threadIdx.x;

  __shared__ float s_q[8 * INNER];
  *(float4*)&s_q[tid * 4] = *(const float4*)&q[(size_t)i0 * INNER + tid * 4];
  __syncthreads();

  const int h = tid >> 6, c = tid & 63;
  float4 w[8];
#pragma unroll
  for (int d4 = 0; d4 < 8; ++d4)
    w[d4] = *(const float4*)&We[(size_t)c * INNER + h * HD + d4 * 4];

#pragma unroll
  for (int il = 0; il < 8; ++il) {
    const float* qh = &s_q[il * INNER + h * HD];
    float acc = 0.f;
#pragma unroll
    for (int d4 = 0; d4 < 8; ++d4) {
      const float4 q4 = *(const float4*)&qh[d4 * 4];
      acc += q4.x * w[d4].x + q4.y * w[d4].y + q4.z * w[d4].z + q4.w * w[d4].w;
    }
    qe[(size_t)(i0 + il) * (NH * EDGE_DIM) + h * EDGE_DIM + c] = acc;
  }

  if (tid < 64) {
    const int il = tid >> 3, h2 = tid & 7;
    float acc = 0.f;
    for (int d = 0; d < HD; ++d)
      acc += s_q[il * INNER + h2 * HD + d] * be[h2 * HD + d];
    qb[(size_t)(i0 + il) * NH + h2] = acc;
  }
}

// ---------------------------------------------------------------------------
// K1: qk[i,h,j] = q_ih . k_jh (unscaled). 16x16 tile, LDS-staged, coalesced.
// ---------------------------------------------------------------------------
__global__ __launch_bounds__(256) void qk_gemm(
    const float* __restrict__ q, const float* __restrict__ k,
    float* __restrict__ qk) {
  const int it = blockIdx.x >> 5, jt = blockIdx.x & 31;
  const int i0 = it * 16, j0 = jt * 16;
  const int tid = threadIdx.x;

  __shared__ float sq[16 * 260];
  __shared__ float sk[16 * 260];
#pragma unroll
  for (int p = 0; p < 4; ++p) {
    const int s = tid + p * 256;
    const int row = s >> 6, c4 = s & 63;
    *(float4*)&sq[row * 260 + c4 * 4] =
        *(const float4*)&q[(size_t)(i0 + row) * INNER + c4 * 4];
    *(float4*)&sk[row * 260 + c4 * 4] =
        *(const float4*)&k[(size_t)(j0 + row) * INNER + c4 * 4];
  }
  __syncthreads();

  const int il = tid >> 4, jl = tid & 15;
  float acc[NH];
#pragma unroll
  for (int h = 0; h < NH; ++h) {
    float s = 0.f;
#pragma unroll
    for (int d4 = 0; d4 < 8; ++d4) {
      const float4 q4 = *(const float4*)&sq[il * 260 + h * HD + d4 * 4];
      const float4 k4 = *(const float4*)&sk[jl * 260 + h * HD + d4 * 4];
      s += q4.x * k4.x + q4.y * k4.y + q4.z * k4.z + q4.w * k4.w;
    }
    acc[h] = s;
  }
#pragma unroll
  for (int h = 0; h < NH; ++h)
    qk[(size_t)(i0 + il) * (NH * N_NODES) + h * N_NODES + j0 + jl] = acc[h];
}

// ---------------------------------------------------------------------------
// K2: single-pass fused attention, scalar accumulators + REGISTER-PREFETCHED
// edges staging (T14 async split: ds_write regs -> issue next chunk's global
// loads -> compute; HBM latency hides under compute of current chunk).
// Block per i, 512 thr, 4 chunks of 128 j; edges read ONCE.
// ---------------------------------------------------------------------------
__global__ __launch_bounds__(512, 4) void fused_attn(
    const float* __restrict__ edges, const int* __restrict__ adjacency,
    const float* __restrict__ v,
    const float* __restrict__ qe, const float* __restrict__ qb,
    const float* __restrict__ qkbuf,
    const float* __restrict__ We, const float* __restrict__ be,
    float* __restrict__ out) {
  const int i   = blockIdx.x;
  const int tid = threadIdx.x;

  __shared__ float s_qe[NH * EDGE_DIM];
  __shared__ float s_qb[NH];
  __shared__ float s_adj[N_NODES];
  __shared__ float e_tile[128 * 68];   // stride 68 floats
  __shared__ float p_lds[NH * 128];
  __shared__ float s_hred[8][2];
  __shared__ float s_rd[NH];
  __shared__ float s_as[NH];
  __shared__ float s_avp[2][INNER];
  __shared__ float s_ae[NH * EDGE_DIM];

  s_qe[tid]  = qe[(size_t)i * (NH * EDGE_DIM) + tid];
  s_adj[tid] = (float)adjacency[(size_t)i * N_NODES + tid];
  if (tid < NH) s_qb[tid] = qb[(size_t)i * NH + tid];

  const int j_l = tid & 127, hg = tid >> 7, h0 = hg * 2;  // phase A
  const int cB  = tid & 63,  hB = tid >> 6;               // phase B
  const int nC  = tid & 255, p2 = tid >> 8, hv = nC >> 5; // phase C

  float hs0 = 0.f, hs1 = 0.f, accv = 0.f, accae = 0.f;

  const float* ebase = edges + (size_t)i * (N_NODES * EDGE_DIM);

  // ---- prologue: prefetch chunk 0 into registers ----
  float4 pref0, pref1, pref2, pref3;
  pref0 = *(const float4*)&ebase[(size_t)(tid +    0) * 4];
  pref1 = *(const float4*)&ebase[(size_t)(tid +  512) * 4];
  pref2 = *(const float4*)&ebase[(size_t)(tid + 1024) * 4];
  pref3 = *(const float4*)&ebase[(size_t)(tid + 1536) * 4];

  for (int jc = 0; jc < 4; ++jc) {
    __syncthreads();  // prior-chunk readers of e_tile/p_lds done

    // ---- ds_write prefetched regs into e_tile ----
    {
      const int s0 = tid, r0 = s0 >> 4, c0 = s0 & 15;
      const int s1 = tid + 512, r1 = s1 >> 4, c1 = s1 & 15;
      const int s2 = tid + 1024, r2 = s2 >> 4, c2 = s2 & 15;
      const int s3 = tid + 1536, r3 = s3 >> 4, c3 = s3 & 15;
      *(float4*)&e_tile[r0 * 68 + c0 * 4] = pref0;
      *(float4*)&e_tile[r1 * 68 + c1 * 4] = pref1;
      *(float4*)&e_tile[r2 * 68 + c2 * 4] = pref2;
      *(float4*)&e_tile[r3 * 68 + c3 * 4] = pref3;
    }
    // ---- issue global loads for chunk jc+1 (in flight during compute) ----
    if (jc < 3) {
      const float* esrc = ebase + (size_t)(jc + 1) * (128 * EDGE_DIM);
      pref0 = *(const float4*)&esrc[(size_t)(tid +    0) * 4];
      pref1 = *(const float4*)&esrc[(size_t)(tid +  512) * 4];
      pref2 = *(const float4*)&esrc[(size_t)(tid + 1024) * 4];
      pref3 = *(const float4*)&esrc[(size_t)(tid + 1536) * 4];
    }
    __syncthreads();  // e_tile ready

    // ---- phase A: p for 2 heads at j = jc*128 + j_l ----
    {
      const float* er  = &e_tile[j_l * 68];
      const float* qe0 = &s_qe[h0 * EDGE_DIM];
      const float* qe1 = qe0 + EDGE_DIM;
      float s0 = 0.f, s1 = 0.f;
#pragma unroll 4
      for (int c4 = 0; c4 < 16; ++c4) {
        const float4 e4 = *(const float4*)&er[c4 * 4];
        const float4 a0 = *(const float4*)&qe0[c4 * 4];
        const float4 a1 = *(const float4*)&qe1[c4 * 4];
        s0 += e4.x * a0.x + e4.y * a0.y + e4.z * a0.z + e4.w * a0.w;
        s1 += e4.x * a1.x + e4.y * a1.y + e4.z * a1.z + e4.w * a1.w;
      }
      const int jg = jc * 128 + j_l;
      const float qk0 = qkbuf[(size_t)i * (NH * N_NODES) + h0 * N_NODES + jg];
      const float qk1 = qkbuf[(size_t)i * (NH * N_NODES) + (h0 + 1) * N_NODES + jg];
      const float aj = s_adj[jg];
      const float p0 = __expf((s0 + qk0 + s_qb[h0]) * SCALE) * aj;
      const float p1 = __expf((s1 + qk1 + s_qb[h0 + 1]) * SCALE) * aj;
      p_lds[h0 * 128 + j_l]       = p0;
      p_lds[(h0 + 1) * 128 + j_l] = p1;
      hs0 += p0; hs1 += p1;
    }
    __syncthreads();  // p_lds ready

    // ---- phase B: accae (scalar) over 128 j for (hB, cB) ----
    {
      const float* pb = &p_lds[hB * 128];
      const float* eb = &e_tile[cB];
#pragma unroll 8
      for (int j4 = 0; j4 < 32; ++j4) {
        const float4 p4 = *(const float4*)&pb[j4 * 4];
        accae = fmaf(p4.x, eb[(j4 * 4 + 0) * 68], accae);
        accae = fmaf(p4.y, eb[(j4 * 4 + 1) * 68], accae);
        accae = fmaf(p4.z, eb[(j4 * 4 + 2) * 68], accae);
        accae = fmaf(p4.w, eb[(j4 * 4 + 3) * 68], accae);
      }
    }
    // ---- phase C: accv (scalar) over 64 j for column nC ----
    {
      const float* vc = v + (size_t)(jc * 128 + p2 * 64) * INNER + nC;
      const float* pr = &p_lds[hv * 128 + p2 * 64];
#pragma unroll 4
      for (int jj4 = 0; jj4 < 16; ++jj4) {
        const float4 p4 = *(const float4*)&pr[jj4 * 4];
        accv = fmaf(p4.x, vc[(size_t)(jj4 * 4 + 0) * INNER], accv);
        accv = fmaf(p4.y, vc[(size_t)(jj4 * 4 + 1) * INNER], accv);
        accv = fmaf(p4.z, vc[(size_t)(jj4 * 4 + 2) * INNER], accv);
        accv = fmaf(p4.w, vc[(size_t)(jj4 * 4 + 3) * INNER], accv);
      }
    }
  }

  // ---- hsum reduction (phase-A roles: waves 2g,2g+1 hold heads 2g,2g+1) ----
  {
    float a = hs0, b = hs1;
#pragma unroll
    for (int off = 32; off > 0; off >>= 1) {
      a += __shfl_xor(a, off, 64);
      b += __shfl_xor(b, off, 64);
    }
    if ((tid & 63) == 0) { s_hred[tid >> 6][0] = a; s_hred[tid >> 6][1] = b; }
  }
  s_avp[p2][nC] = accv;
  __syncthreads();
  if (tid < NH) {
    const int g = tid >> 1, r = tid & 1;
    const float t = s_hred[g * 2][r] + s_hred[g * 2 + 1][r];
    s_rd[tid] = (t == 0.f) ? 1.f : (1.f / t);
    s_as[tid] = (t == 0.f) ? 0.f : 1.f;
  }
  __syncthreads();

  // ---- normalized ae (index h*64+c == tid) ----
  s_ae[tid] = accae * s_rd[hB];
  __syncthreads();

  // ---- epilogue ----
  if (tid < INNER) {
    const int n = tid, h = n >> 5;
    float o = (s_avp[0][n] + s_avp[1][n]) * s_rd[h] + s_as[h] * be[n];
    const float* aeh = &s_ae[h * EDGE_DIM];
#pragma unroll 8
    for (int cc = 0; cc < EDGE_DIM; ++cc)
      o = fmaf(aeh[cc], We[(size_t)cc * INNER + n], o);
    out[(size_t)i * INNER + n] = o;
  }
}

extern "C" void kernel_launch(void* const* d_in, const int* in_sizes, int n_in,
                              void* d_out, int out_size, void* d_ws, size_t ws_size,
                              hipStream_t stream) {
  const float* nodes     = (const float*)d_in[0];
  const float* edges     = (const float*)d_in[1];
  const int*   adjacency = (const int*)d_in[2];
  const float* Wq = (const float*)d_in[3];
  const float* bq = (const float*)d_in[4];
  const float* Wk = (const float*)d_in[5];
  const float* bk = (const float*)d_in[6];
  const float* Wv = (const float*)d_in[7];
  const float* bv = (const float*)d_in[8];
  const float* We = (const float*)d_in[9];
  const float* be = (const float*)d_in[10];

  float* q   = (float*)d_ws;                           // 512*256
  float* k   = q   + (size_t)N_NODES * INNER;          // 512*256
  float* v   = k   + (size_t)N_NODES * INNER;          // 512*256
  float* qe  = v   + (size_t)N_NODES * INNER;          // 512*512
  float* qb  = qe  + (size_t)N_NODES * NH * EDGE_DIM;  // 512*8
  float* qkb = qb  + (size_t)N_NODES * NH;             // 512*8*512

  proj_qkv<<<dim3(3 * 64), dim3(256), 0, stream>>>(
      nodes, Wq, bq, Wk, bk, Wv, bv, q, k, v);
  qe_qb<<<dim3(64), dim3(512), 0, stream>>>(q, We, be, qe, qb);
  qk_gemm<<<dim3(1024), dim3(256), 0, stream>>>(q, k, qkb);
  fused_attn<<<dim3(N_NODES), dim3(512), 0, stream>>>(
      edges, adjacency, v, qe, qb, qkb, We, be, (float*)d_out);
}

// Round 9
// 153.568 us; speedup vs baseline: 1.8750x; 1.0305x over previous
//
#include <hip/hip_runtime.h>

#define N_NODES 512
#define INNER   256
#define IN_DIM  128
#define EDGE_DIM 64
#define NH 8
#define HD 32
#define SCALE 0.17677669529663687f  // 1/sqrt(32)

// ---------------------------------------------------------------------------
// K0: q/k/v projections. Block (m, i-tile of 8). 192 blocks x 256 thr.
// ---------------------------------------------------------------------------
__global__ __launch_bounds__(256) void proj_qkv(
    const float* __restrict__ nodes,
    const float* __restrict__ Wq, const float* __restrict__ bq,
    const float* __restrict__ Wk, const float* __restrict__ bk,
    const float* __restrict__ Wv, const float* __restrict__ bv,
    float* __restrict__ q, float* __restrict__ k, float* __restrict__ v) {
  const int m  = blockIdx.x >> 6;
  const int i0 = (blockIdx.x & 63) * 8;
  const int n  = threadIdx.x;
  const float* __restrict__ W = (m == 0) ? Wq : (m == 1) ? Wk : Wv;
  const float* __restrict__ b = (m == 0) ? bq : (m == 1) ? bk : bv;
  float*       __restrict__ o = (m == 0) ? q  : (m == 1) ? k  : v;

  __shared__ float s_n[8 * IN_DIM];
  *(float4*)&s_n[n * 4] = *(const float4*)&nodes[(size_t)i0 * IN_DIM + n * 4];
  __syncthreads();

  float acc[8] = {0.f, 0.f, 0.f, 0.f, 0.f, 0.f, 0.f, 0.f};
#pragma unroll 4
  for (int c = 0; c < IN_DIM; ++c) {
    const float w = W[(size_t)c * INNER + n];
#pragma unroll
    for (int r = 0; r < 8; ++r) acc[r] = fmaf(s_n[r * IN_DIM + c], w, acc[r]);
  }
  const float bn = b[n];
#pragma unroll
  for (int r = 0; r < 8; ++r) o[(size_t)(i0 + r) * INNER + n] = acc[r] + bn;
}

// ---------------------------------------------------------------------------
// K0b: qe[i,h,c] = q_ih . We[c, h*32..]; qb[i,h] = q_ih . be_h.
// ---------------------------------------------------------------------------
__global__ __launch_bounds__(512) void qe_qb(
    const float* __restrict__ q, const float* __restrict__ We,
    const float* __restrict__ be,
    float* __restrict__ qe, float* __restrict__ qb) {
  const int i0  = blockIdx.x * 8;
  const int tid = threadIdx.x;

  __shared__ float s_q[8 * INNER];
  *(float4*)&s_q[tid * 4] = *(const float4*)&q[(size_t)i0 * INNER + tid * 4];
  __syncthreads();

  const int h = tid >> 6, c = tid & 63;
  float4 w[8];
#pragma unroll
  for (int d4 = 0; d4 < 8; ++d4)
    w[d4] = *(const float4*)&We[(size_t)c * INNER + h * HD + d4 * 4];

#pragma unroll
  for (int il = 0; il < 8; ++il) {
    const float* qh = &s_q[il * INNER + h * HD];
    float acc = 0.f;
#pragma unroll
    for (int d4 = 0; d4 < 8; ++d4) {
      const float4 q4 = *(const float4*)&qh[d4 * 4];
      acc += q4.x * w[d4].x + q4.y * w[d4].y + q4.z * w[d4].z + q4.w * w[d4].w;
    }
    qe[(size_t)(i0 + il) * (NH * EDGE_DIM) + h * EDGE_DIM + c] = acc;
  }

  if (tid < 64) {
    const int il = tid >> 3, h2 = tid & 7;
    float acc = 0.f;
    for (int d = 0; d < HD; ++d)
      acc += s_q[il * INNER + h2 * HD + d] * be[h2 * HD + d];
    qb[(size_t)(i0 + il) * NH + h2] = acc;
  }
}

// ---------------------------------------------------------------------------
// K1: qk[i,h,j] = q_ih . k_jh (unscaled). 16x16 tile, LDS-staged, coalesced.
// ---------------------------------------------------------------------------
__global__ __launch_bounds__(256) void qk_gemm(
    const float* __restrict__ q, const float* __restrict__ k,
    float* __restrict__ qk) {
  const int it = blockIdx.x >> 5, jt = blockIdx.x & 31;
  const int i0 = it * 16, j0 = jt * 16;
  const int tid = threadIdx.x;

  __shared__ float sq[16 * 260];
  __shared__ float sk[16 * 260];
#pragma unroll
  for (int p = 0; p < 4; ++p) {
    const int s = tid + p * 256;
    const int row = s >> 6, c4 = s & 63;
    *(float4*)&sq[row * 260 + c4 * 4] =
        *(const float4*)&q[(size_t)(i0 + row) * INNER + c4 * 4];
    *(float4*)&sk[row * 260 + c4 * 4] =
        *(const float4*)&k[(size_t)(j0 + row) * INNER + c4 * 4];
  }
  __syncthreads();

  const int il = tid >> 4, jl = tid & 15;
  float acc[NH];
#pragma unroll
  for (int h = 0; h < NH; ++h) {
    float s = 0.f;
#pragma unroll
    for (int d4 = 0; d4 < 8; ++d4) {
      const float4 q4 = *(const float4*)&sq[il * 260 + h * HD + d4 * 4];
      const float4 k4 = *(const float4*)&sk[jl * 260 + h * HD + d4 * 4];
      s += q4.x * k4.x + q4.y * k4.y + q4.z * k4.z + q4.w * k4.w;
    }
    acc[h] = s;
  }
#pragma unroll
  for (int h = 0; h < NH; ++h)
    qk[(size_t)(i0 + il) * (NH * N_NODES) + h * N_NODES + j0 + jl] = acc[h];
}

// ---------------------------------------------------------------------------
// K2: single-pass fused attention. Phase B VECTORIZED (float4 ae accum,
// 4-way j-split) -> LDS instruction pressure cut ~2.3x (the round-8 bound).
// Block per i, 512 thr, 4 chunks of 128 j; edges read ONCE.
// ---------------------------------------------------------------------------
__global__ __launch_bounds__(512, 4) void fused_attn(
    const float* __restrict__ edges, const int* __restrict__ adjacency,
    const float* __restrict__ v,
    const float* __restrict__ qe, const float* __restrict__ qb,
    const float* __restrict__ qkbuf,
    const float* __restrict__ We, const float* __restrict__ be,
    float* __restrict__ out) {
  const int i   = blockIdx.x;
  const int tid = threadIdx.x;

  __shared__ float s_qe[NH * EDGE_DIM];
  __shared__ float s_qb[NH];
  __shared__ float s_adj[N_NODES];
  __shared__ float e_tile[128 * 68];   // stride 68 floats
  __shared__ float p_lds[NH * 128];
  __shared__ float s_hred[8][2];
  __shared__ float s_rd[NH];
  __shared__ float s_as[NH];
  __shared__ float s_avp[2][INNER];
  __shared__ float s_aep[4][NH * EDGE_DIM];  // per-j-quarter ae partials
  __shared__ float s_ae[NH * EDGE_DIM];

  s_qe[tid]  = qe[(size_t)i * (NH * EDGE_DIM) + tid];
  s_adj[tid] = (float)adjacency[(size_t)i * N_NODES + tid];
  if (tid < NH) s_qb[tid] = qb[(size_t)i * NH + tid];

  const int j_l = tid & 127, hg = tid >> 7, h0 = hg * 2;   // phase A
  const int jqB = tid >> 7, hB = (tid >> 4) & 7, cgB = tid & 15;  // phase B
  const int nC  = tid & 255, p2 = tid >> 8, hv = nC >> 5;  // phase C

  float hs0 = 0.f, hs1 = 0.f, accv = 0.f;
  float4 accae4 = {0.f, 0.f, 0.f, 0.f};

  const float* ebase = edges + (size_t)i * (N_NODES * EDGE_DIM);

  // ---- prologue: prefetch chunk 0 into registers ----
  float4 pref0, pref1, pref2, pref3;
  pref0 = *(const float4*)&ebase[(size_t)(tid +    0) * 4];
  pref1 = *(const float4*)&ebase[(size_t)(tid +  512) * 4];
  pref2 = *(const float4*)&ebase[(size_t)(tid + 1024) * 4];
  pref3 = *(const float4*)&ebase[(size_t)(tid + 1536) * 4];

  for (int jc = 0; jc < 4; ++jc) {
    __syncthreads();  // prior-chunk readers of e_tile/p_lds done

    // ---- ds_write prefetched regs into e_tile ----
    {
      const int s0 = tid, r0 = s0 >> 4, c0 = s0 & 15;
      const int s1 = tid + 512, r1 = s1 >> 4, c1 = s1 & 15;
      const int s2 = tid + 1024, r2 = s2 >> 4, c2 = s2 & 15;
      const int s3 = tid + 1536, r3 = s3 >> 4, c3 = s3 & 15;
      *(float4*)&e_tile[r0 * 68 + c0 * 4] = pref0;
      *(float4*)&e_tile[r1 * 68 + c1 * 4] = pref1;
      *(float4*)&e_tile[r2 * 68 + c2 * 4] = pref2;
      *(float4*)&e_tile[r3 * 68 + c3 * 4] = pref3;
    }
    // ---- issue global loads for chunk jc+1 (in flight during compute) ----
    if (jc < 3) {
      const float* esrc = ebase + (size_t)(jc + 1) * (128 * EDGE_DIM);
      pref0 = *(const float4*)&esrc[(size_t)(tid +    0) * 4];
      pref1 = *(const float4*)&esrc[(size_t)(tid +  512) * 4];
      pref2 = *(const float4*)&esrc[(size_t)(tid + 1024) * 4];
      pref3 = *(const float4*)&esrc[(size_t)(tid + 1536) * 4];
    }
    __syncthreads();  // e_tile ready

    // ---- phase A: p for 2 heads at j = jc*128 + j_l ----
    {
      const float* er  = &e_tile[j_l * 68];
      const float* qe0 = &s_qe[h0 * EDGE_DIM];
      const float* qe1 = qe0 + EDGE_DIM;
      float s0 = 0.f, s1 = 0.f;
#pragma unroll 4
      for (int c4 = 0; c4 < 16; ++c4) {
        const float4 e4 = *(const float4*)&er[c4 * 4];
        const float4 a0 = *(const float4*)&qe0[c4 * 4];
        const float4 a1 = *(const float4*)&qe1[c4 * 4];
        s0 += e4.x * a0.x + e4.y * a0.y + e4.z * a0.z + e4.w * a0.w;
        s1 += e4.x * a1.x + e4.y * a1.y + e4.z * a1.z + e4.w * a1.w;
      }
      const int jg = jc * 128 + j_l;
      const float qk0 = qkbuf[(size_t)i * (NH * N_NODES) + h0 * N_NODES + jg];
      const float qk1 = qkbuf[(size_t)i * (NH * N_NODES) + (h0 + 1) * N_NODES + jg];
      const float aj = s_adj[jg];
      const float p0 = __expf((s0 + qk0 + s_qb[h0]) * SCALE) * aj;
      const float p1 = __expf((s1 + qk1 + s_qb[h0 + 1]) * SCALE) * aj;
      p_lds[h0 * 128 + j_l]       = p0;
      p_lds[(h0 + 1) * 128 + j_l] = p1;
      hs0 += p0; hs1 += p1;
    }
    __syncthreads();  // p_lds ready

    // ---- phase B (vectorized): accae4 over 32 j for (hB, cols cgB*4..+3) ----
    {
      const float* pb = &p_lds[hB * 128 + jqB * 32];
      const float* eb = &e_tile[(jqB * 32) * 68 + cgB * 4];
#pragma unroll 4
      for (int j8 = 0; j8 < 8; ++j8) {
        const float4 p4 = *(const float4*)&pb[j8 * 4];
        const float4 e0 = *(const float4*)&eb[(size_t)(j8 * 4 + 0) * 68];
        const float4 e1 = *(const float4*)&eb[(size_t)(j8 * 4 + 1) * 68];
        const float4 e2 = *(const float4*)&eb[(size_t)(j8 * 4 + 2) * 68];
        const float4 e3 = *(const float4*)&eb[(size_t)(j8 * 4 + 3) * 68];
        accae4.x = fmaf(p4.x, e0.x, accae4.x);
        accae4.y = fmaf(p4.x, e0.y, accae4.y);
        accae4.z = fmaf(p4.x, e0.z, accae4.z);
        accae4.w = fmaf(p4.x, e0.w, accae4.w);
        accae4.x = fmaf(p4.y, e1.x, accae4.x);
        accae4.y = fmaf(p4.y, e1.y, accae4.y);
        accae4.z = fmaf(p4.y, e1.z, accae4.z);
        accae4.w = fmaf(p4.y, e1.w, accae4.w);
        accae4.x = fmaf(p4.z, e2.x, accae4.x);
        accae4.y = fmaf(p4.z, e2.y, accae4.y);
        accae4.z = fmaf(p4.z, e2.z, accae4.z);
        accae4.w = fmaf(p4.z, e2.w, accae4.w);
        accae4.x = fmaf(p4.w, e3.x, accae4.x);
        accae4.y = fmaf(p4.w, e3.y, accae4.y);
        accae4.z = fmaf(p4.w, e3.z, accae4.z);
        accae4.w = fmaf(p4.w, e3.w, accae4.w);
      }
    }
    // ---- phase C: accv (scalar) over 64 j for column nC ----
    {
      const float* vc = v + (size_t)(jc * 128 + p2 * 64) * INNER + nC;
      const float* pr = &p_lds[hv * 128 + p2 * 64];
#pragma unroll 4
      for (int jj4 = 0; jj4 < 16; ++jj4) {
        const float4 p4 = *(const float4*)&pr[jj4 * 4];
        accv = fmaf(p4.x, vc[(size_t)(jj4 * 4 + 0) * INNER], accv);
        accv = fmaf(p4.y, vc[(size_t)(jj4 * 4 + 1) * INNER], accv);
        accv = fmaf(p4.z, vc[(size_t)(jj4 * 4 + 2) * INNER], accv);
        accv = fmaf(p4.w, vc[(size_t)(jj4 * 4 + 3) * INNER], accv);
      }
    }
  }

  // ---- publish partials ----
  {
    float a = hs0, b = hs1;
#pragma unroll
    for (int off = 32; off > 0; off >>= 1) {
      a += __shfl_xor(a, off, 64);
      b += __shfl_xor(b, off, 64);
    }
    if ((tid & 63) == 0) { s_hred[tid >> 6][0] = a; s_hred[tid >> 6][1] = b; }
  }
  s_avp[p2][nC] = accv;
  *(float4*)&s_aep[jqB][hB * EDGE_DIM + cgB * 4] = accae4;
  __syncthreads();
  if (tid < NH) {
    const int g = tid >> 1, r = tid & 1;
    const float t = s_hred[g * 2][r] + s_hred[g * 2 + 1][r];
    s_rd[tid] = (t == 0.f) ? 1.f : (1.f / t);
    s_as[tid] = (t == 0.f) ? 0.f : 1.f;
  }
  __syncthreads();

  // ---- combine ae partials, normalize (tid == h*64+c) ----
  s_ae[tid] = (s_aep[0][tid] + s_aep[1][tid] + s_aep[2][tid] + s_aep[3][tid])
              * s_rd[tid >> 6];
  __syncthreads();

  // ---- epilogue ----
  if (tid < INNER) {
    const int n = tid, h = n >> 5;
    float o = (s_avp[0][n] + s_avp[1][n]) * s_rd[h] + s_as[h] * be[n];
    const float* aeh = &s_ae[h * EDGE_DIM];
#pragma unroll 8
    for (int cc = 0; cc < EDGE_DIM; ++cc)
      o = fmaf(aeh[cc], We[(size_t)cc * INNER + n], o);
    out[(size_t)i * INNER + n] = o;
  }
}

extern "C" void kernel_launch(void* const* d_in, const int* in_sizes, int n_in,
                              void* d_out, int out_size, void* d_ws, size_t ws_size,
                              hipStream_t stream) {
  const float* nodes     = (const float*)d_in[0];
  const float* edges     = (const float*)d_in[1];
  const int*   adjacency = (const int*)d_in[2];
  const float* Wq = (const float*)d_in[3];
  const float* bq = (const float*)d_in[4];
  const float* Wk = (const float*)d_in[5];
  const float* bk = (const float*)d_in[6];
  const float* Wv = (const float*)d_in[7];
  const float* bv = (const float*)d_in[8];
  const float* We = (const float*)d_in[9];
  const float* be = (const float*)d_in[10];

  float* q   = (float*)d_ws;                           // 512*256
  float* k   = q   + (size_t)N_NODES * INNER;          // 512*256
  float* v   = k   + (size_t)N_NODES * INNER;          // 512*256
  float* qe  = v   + (size_t)N_NODES * INNER;          // 512*512
  float* qb  = qe  + (size_t)N_NODES * NH * EDGE_DIM;  // 512*8
  float* qkb = qb  + (size_t)N_NODES * NH;             // 512*8*512

  proj_qkv<<<dim3(3 * 64), dim3(256), 0, stream>>>(
      nodes, Wq, bq, Wk, bk, Wv, bv, q, k, v);
  qe_qb<<<dim3(64), dim3(512), 0, stream>>>(q, We, be, qe, qb);
  qk_gemm<<<dim3(1024), dim3(256), 0, stream>>>(q, k, qkb);
  fused_attn<<<dim3(N_NODES), dim3(512), 0, stream>>>(
      edges, adjacency, v, qe, qb, qkb, We, be, (float*)d_out);
}